// Round 8
// baseline (442.787 us; speedup 1.0000x reference)
//
#include <hip/hip_runtime.h>
#include <cstdint>

// SpikeFP64Sqrt: rows of 64 float pulses (MSB-first fp64 bits) -> sqrt via
// exponent-halving guess + 12 IEEE fp64 Newton iterations -> pulses out.
//
// R7 post-mortem: split kernels (pure-read then pure-write streams) beat the
// fused structure ~128 vs ~145us -- DRAM stream separation confirmed. Still
// ~1.5x over the 85us byte floor.
// R8: (1) kernel1 uses PLAIN loads again: the harness restores d_in with a
// 268MB copy right before each timed run, so input lines sit in L3; R7's nt
// loads told the cache not to keep them (anti-optimization -- R2 FETCH_SIZE
// proved L3 serves ~half the input when allowed). (2) kernel2 processes 128
// rows/wave with both word-loads in flight -> longer consecutive store runs,
// fill-kernel-shaped (fill sustains 6.5TB/s).

#pragma clang fp contract(off)   // no FMA contraction anywhere (bit-exact fp64)

typedef float f32x4 __attribute__((ext_vector_type(4)));

static constexpr uint64_t kSqrt2Mant = 1865452045155277ULL;
static constexpr uint64_t kNanBits   = 0x7FF8000000000000ULL;
static constexpr uint64_t kInfBits   = 0x7FF0000000000000ULL;
static constexpr uint64_t kMantMask  = 0xFFFFFFFFFFFFFULL;

// ---------------- kernel 1: pulses -> packed u64 -> sqrt -> word buffer ----
__global__ __launch_bounds__(256) void spike_sqrt_pack_kernel(
    const float* __restrict__ x, uint64_t* __restrict__ w, int rows) {
  const int lane   = threadIdx.x & 63;
  const int waveId = (int)blockIdx.x * 4 + (threadIdx.x >> 6);
  const long long waveRow0 = (long long)waveId * 64;
  const int col = lane ^ 63;   // lane j reads pulse (63-j): ballot bit j == MSB-first bit j

  uint64_t u = 0;
  const bool fullWave = (waveRow0 + 64) <= (long long)rows;
  if (fullWave) {
    const float* base = x + waveRow0 * 64 + col;
#pragma unroll
    for (int b = 0; b < 2; ++b) {
      float v[32];
#pragma unroll
      for (int k = 0; k < 32; ++k)             // 32 loads in flight, L3-served
        v[k] = base[(size_t)(b * 32 + k) * 64];
#pragma unroll
      for (int k = 0; k < 32; ++k) {
        unsigned long long m = __ballot(v[k] > 0.5f);
        if (lane == b * 32 + k) u = m;
      }
    }
  } else {
#pragma unroll 4
    for (int rr = 0; rr < 64; ++rr) {
      const long long row = waveRow0 + rr;
      float v = (row < (long long)rows) ? x[row * 64 + col] : 0.0f;
      unsigned long long m = __ballot(v > 0.5f);
      if (lane == rr) u = m;
    }
  }

  // ---- per-lane fp64 sqrt, bit-exact vs reference ----
  const double f = __longlong_as_double((long long)u);

  const int e_x    = (int)((u >> 52) & 0x7FF);
  const int e_real = e_x - 1023;                       // 11-bit two's complement
  const long long e_half = ((long long)e_real) >> 1;   // arithmetic shift = floor/2
  const uint64_t mant = ((e_real & 1) != 0) ? kSqrt2Mant : 0ULL;
  const uint64_t ybits = (((uint64_t)(e_half + 1023)) << 52) | mant;
  double y = __longlong_as_double((long long)ybits);

#pragma unroll
  for (int it = 0; it < 12; ++it) {
    y = 0.5 * (y + f / y);                             // IEEE fp64, no contraction
  }

  uint64_t r = (uint64_t)__double_as_longlong(y);
  const bool is_neg    = (u >> 63) != 0;
  const bool m_any     = (u & kMantMask) != 0;
  const bool e_all_one = (e_x == 0x7FF);
  const bool e_is_zero = (e_x == 0);
  if (is_neg) r = kNanBits;                            // same override order as ref
  if (e_all_one && m_any) r = kNanBits;
  if (e_all_one && !m_any && !is_neg) r = kInfBits;
  if (e_is_zero && !m_any) r = 0ULL;

  const long long myRow = waveRow0 + lane;
  if (myRow < (long long)rows) w[myRow] = r;           // coalesced dwordx2, 512B/wave
}

// ------- kernel 2: word buffer -> pulse expansion, 128 rows per wave -------
__global__ __launch_bounds__(256) void spike_unpack_kernel(
    const uint64_t* __restrict__ w, float* __restrict__ out, int rows) {
  const int lane   = threadIdx.x & 63;
  const int waveId = (int)blockIdx.x * 4 + (threadIdx.x >> 6);
  const long long waveRow0 = (long long)waveId * 128;

  // both word-loads issued before any use
  const long long row0 = waveRow0 + lane;
  const long long row1 = waveRow0 + 64 + lane;
  const uint64_t r0 = (row0 < (long long)rows) ? w[row0] : 0ULL;
  const uint64_t r1 = (row1 < (long long)rows) ? w[row1] : 0ULL;

  const int c0 = (lane & 15) * 4;                      // pulse index of o.x
#pragma unroll
  for (int s = 0; s < 2; ++s) {
    const long long rl = (long long)(s == 0 ? r0 : r1);
    const long long base = waveRow0 + s * 64;
#pragma unroll
    for (int t = 0; t < 16; ++t) {
      const int srcRow = 4 * t + (lane >> 4);          // 0..63 within the word set
      const uint64_t b = (uint64_t)__shfl(rl, srcRow, 64);
      f32x4 o;
      o.x = (float)((b >> (63 - c0)) & 1ULL);
      o.y = (float)((b >> (62 - c0)) & 1ULL);
      o.z = (float)((b >> (61 - c0)) & 1ULL);
      o.w = (float)((b >> (60 - c0)) & 1ULL);
      const long long row = base + srcRow;
      if (row < (long long)rows) {
        *reinterpret_cast<f32x4*>(out + row * 64 + c0) = o;   // 1KB per instr
      }
    }
  }
}

extern "C" void kernel_launch(void* const* d_in, const int* in_sizes, int n_in,
                              void* d_out, int out_size, void* d_ws, size_t ws_size,
                              hipStream_t stream) {
  const float* x = (const float*)d_in[0];
  float* out = (float*)d_out;
  uint64_t* words = (uint64_t*)d_ws;                   // rows*8 bytes (8MB) scratch
  const int rows = in_sizes[0] / 64;                   // 64 pulses per fp64
  const int grid1 = (rows + 255) / 256;                // 4 waves * 64 rows
  const int grid2 = (rows + 511) / 512;                // 4 waves * 128 rows
  spike_sqrt_pack_kernel<<<grid1, 256, 0, stream>>>(x, words, rows);
  spike_unpack_kernel<<<grid2, 256, 0, stream>>>(words, out, rows);
}

// Round 9
// 423.704 us; speedup vs baseline: 1.0450x; 1.0450x over previous
//
#include <hip/hip_runtime.h>
#include <cstdint>

// SpikeFP64Sqrt: rows of 64 float pulses (MSB-first fp64 bits) -> sqrt via
// exponent-halving guess + 12 IEEE fp64 Newton iterations -> pulses out.
//
// R8 post-mortem: plain loads + 128-row unpack REGRESSED (+23us). nt input
// loads are genuinely good: the poison fill leaves d_out dirty across all of
// L3; plain loads allocate and force eviction-writebacks of those lines.
// R9 = R7 structure (split kernels, nt reads, 64-row unpack) with kernel1's
// read stream widened to 16B/lane nt dwordx4 (16 VMEM instrs / 64-row tile,
// all in flight) -- every measured 6.3-6.5TB/s stream on this chip used
// 16B/lane; R7 kernel1 used 4B/lane dwords. Pack = per-lane nibble from 4
// pulses + 4-step shfl_xor OR over the 16-lane row group; lane j keeps
// iteration t==(lane&15) ending with row 4*(lane&15)+(lane>>4) (permutation;
// Newton phase is lane-symmetric, store uses the permuted index).

#pragma clang fp contract(off)   // no FMA contraction anywhere (bit-exact fp64)

typedef float    f32x4 __attribute__((ext_vector_type(4)));
typedef uint32_t u32x4 __attribute__((ext_vector_type(4)));

static constexpr uint64_t kSqrt2Mant = 1865452045155277ULL;
static constexpr uint64_t kNanBits   = 0x7FF8000000000000ULL;
static constexpr uint64_t kInfBits   = 0x7FF0000000000000ULL;
static constexpr uint64_t kMantMask  = 0xFFFFFFFFFFFFFULL;

// ---------------- kernel 1: pulses -> packed u64 -> sqrt -> word buffer ----
__global__ __launch_bounds__(256) void spike_sqrt_pack_kernel(
    const float* __restrict__ x, uint64_t* __restrict__ w, int rows) {
  const int lane   = threadIdx.x & 63;
  const int waveId = (int)blockIdx.x * 4 + (threadIdx.x >> 6);
  const long long waveRow0 = (long long)waveId * 64;

  uint64_t u = 0;
  long long myRow;
  const bool fullWave = (waveRow0 + 64) <= (long long)rows;
  if (fullWave) {
    // 16 nt dwordx4 loads stage the whole 16KB tile (1KB = 4 rows per instr)
    const u32x4* gbase = (const u32x4*)(x + waveRow0 * 64) + lane;
    u32x4 v[16];
#pragma unroll
    for (int t = 0; t < 16; ++t)
      v[t] = __builtin_nontemporal_load(gbase + (size_t)t * 64);

    const int chunk = lane & 15;          // 16B chunk within my row
    const int grp   = lane >> 4;          // which of the 4 rows this instr held
#pragma unroll
    for (int t = 0; t < 16; ++t) {
      // nibble for pulses 4*chunk .. 4*chunk+3 of row 4t+grp (1.0f bit23=1)
      const uint32_t b0 = (v[t].x >> 23) & 1u;
      const uint32_t b1 = (v[t].y >> 23) & 1u;
      const uint32_t b2 = (v[t].z >> 23) & 1u;
      const uint32_t b3 = (v[t].w >> 23) & 1u;
      const uint32_t nib = (b0 << 3) | (b1 << 2) | (b2 << 1) | b3;
      uint64_t pw = (uint64_t)nib << (60 - 4 * chunk);   // pulse p -> bit 63-p
      // OR-reduce over the 16-lane row group (lanes differing in bits 0..3)
      pw |= __shfl_xor((unsigned long long)pw, 1, 64);
      pw |= __shfl_xor((unsigned long long)pw, 2, 64);
      pw |= __shfl_xor((unsigned long long)pw, 4, 64);
      pw |= __shfl_xor((unsigned long long)pw, 8, 64);
      if (chunk == t) u = pw;             // lane keeps its assigned iteration
    }
    myRow = waveRow0 + 4 * chunk + grp;   // permutation of the 64 tile rows
  } else {
    // tail fallback (unused at this size): serial ballot pack
    const int col = lane ^ 63;
#pragma unroll 4
    for (int rr = 0; rr < 64; ++rr) {
      const long long row = waveRow0 + rr;
      float vv = (row < (long long)rows) ? x[row * 64 + col] : 0.0f;
      unsigned long long m = __ballot(vv > 0.5f);
      if (lane == rr) u = m;
    }
    myRow = waveRow0 + lane;
  }

  // ---- per-lane fp64 sqrt, bit-exact vs reference ----
  const double f = __longlong_as_double((long long)u);

  const int e_x    = (int)((u >> 52) & 0x7FF);
  const int e_real = e_x - 1023;                       // 11-bit two's complement
  const long long e_half = ((long long)e_real) >> 1;   // arithmetic shift = floor/2
  const uint64_t mant = ((e_real & 1) != 0) ? kSqrt2Mant : 0ULL;
  const uint64_t ybits = (((uint64_t)(e_half + 1023)) << 52) | mant;
  double y = __longlong_as_double((long long)ybits);

#pragma unroll
  for (int it = 0; it < 12; ++it) {
    y = 0.5 * (y + f / y);                             // IEEE fp64, no contraction
  }

  uint64_t r = (uint64_t)__double_as_longlong(y);
  const bool is_neg    = (u >> 63) != 0;
  const bool m_any     = (u & kMantMask) != 0;
  const bool e_all_one = (e_x == 0x7FF);
  const bool e_is_zero = (e_x == 0);
  if (is_neg) r = kNanBits;                            // same override order as ref
  if (e_all_one && m_any) r = kNanBits;
  if (e_all_one && !m_any && !is_neg) r = kInfBits;
  if (e_is_zero && !m_any) r = 0ULL;

  if (myRow < (long long)rows) w[myRow] = r;           // 512B/wave (permuted in-segment)
}

// ---------------- kernel 2: word buffer -> pulse expansion (write stream) --
__global__ __launch_bounds__(256) void spike_unpack_kernel(
    const uint64_t* __restrict__ w, float* __restrict__ out, int rows) {
  const int lane   = threadIdx.x & 63;
  const int waveId = (int)blockIdx.x * 4 + (threadIdx.x >> 6);
  const long long waveRow0 = (long long)waveId * 64;

  const long long myRow = waveRow0 + lane;
  const uint64_t r = (myRow < (long long)rows) ? w[myRow] : 0ULL;
  const long long rl = (long long)r;

#pragma unroll
  for (int t = 0; t < 16; ++t) {
    const int srcRow = 4 * t + (lane >> 4);            // 0..63 within the wave
    const uint64_t b = (uint64_t)__shfl(rl, srcRow, 64);
    const int c0 = (lane & 15) * 4;                    // pulse index of o.x
    f32x4 o;
    o.x = (float)((b >> (63 - c0)) & 1ULL);
    o.y = (float)((b >> (62 - c0)) & 1ULL);
    o.z = (float)((b >> (61 - c0)) & 1ULL);
    o.w = (float)((b >> (60 - c0)) & 1ULL);
    const long long row = waveRow0 + srcRow;
    if (row < (long long)rows) {
      *reinterpret_cast<f32x4*>(out + row * 64 + c0) = o;   // 1KB per instr
    }
  }
}

extern "C" void kernel_launch(void* const* d_in, const int* in_sizes, int n_in,
                              void* d_out, int out_size, void* d_ws, size_t ws_size,
                              hipStream_t stream) {
  const float* x = (const float*)d_in[0];
  float* out = (float*)d_out;
  uint64_t* words = (uint64_t*)d_ws;                   // rows*8 bytes (8MB) scratch
  const int rows = in_sizes[0] / 64;                   // 64 pulses per fp64
  const int grid = (rows + 255) / 256;                 // 4 waves * 64 rows
  spike_sqrt_pack_kernel<<<grid, 256, 0, stream>>>(x, words, rows);
  spike_unpack_kernel<<<grid, 256, 0, stream>>>(words, out, rows);
}